// Round 10
// baseline (662.253 us; speedup 1.0000x reference)
//
#include <hip/hip_runtime.h>

// ---------------------------------------------------------------------------
// STFT-Fourier-KAN DGCNN on MI355X.
// R9 bench was an infra failure (container acquisition died; kernel never
// ran) — resubmitting unchanged, same as the R5/R6 -> R7 precedent.
// R8: 560 us. kan_kernel<2> = 211 us with ALL pipes idle (Mfma 9%, VALU 18%,
// HBM 4%) -> barrier/latency bound: 2 barriers x 70 chunks, scattered global
// loads feeding cos/sin inside the staged A-tile, 2.5 blocks/CU.
// R9/R10: barrier-free KAN layers. Each lane computes its OWN A-fragment in
// registers (A is wave-partitioned; frag layout A[m=lane&15][k=quad*8+j]
// means lane needs pairs c*16+kb*4+{0..3} of its own row) and loads B
// fragments directly from global (16B per nb, L1/L2-resident). No Abuf/Bbuf,
// no __syncthreads in the K-loop. Per-pair (hidx, ham*k) LDS tables.
// Also: seg_kernel split into 256-block partial + combine (was 1 block/CU
// streaming 1 MB serially).
// ---------------------------------------------------------------------------

typedef unsigned short u16;
typedef unsigned int   u32;
typedef unsigned long long u64;
typedef __attribute__((ext_vector_type(8))) _Float16 half8;
typedef __attribute__((ext_vector_type(4))) float f32x4;

__device__ __forceinline__ float bf2f(u16 u) {
  u32 v = ((u32)u) << 16;
  return __uint_as_float(v);
}
__device__ __forceinline__ u16 f2bfr(float f) {  // bf16 round-to-nearest-even
  u32 x = __float_as_uint(f);
  u32 r = x + 0x7FFFu + ((x >> 16) & 1u);
  return (u16)(r >> 16);
}
__device__ __forceinline__ u16 f2h(float f) {    // fp16 RTN bits
  _Float16 h = (_Float16)f;
  u16 r;
  __builtin_memcpy(&r, &h, 2);
  return r;
}
__device__ __forceinline__ float h2f(u16 u) {
  _Float16 h;
  __builtin_memcpy(&h, &u, 2);
  return (float)h;
}
// dtype-dispatched external load (flag wave-uniform -> scalar branch)
__device__ __forceinline__ float ldf(const void* p, size_t i, bool f32) {
  return f32 ? ((const float*)p)[i] : bf2f(((const u16*)p)[i]);
}
__device__ __forceinline__ u64 minu64(u64 a, u64 b) { return a < b ? a : b; }

// ---------------- workspace layout (bytes) ----------------
#define NBR_OFF   ((size_t)0)                       // int32 [163840]       655,360
#define FLAG_OFF  ((size_t)917504)                  // int32 [1]
#define XG_OFF    ((size_t)(1u << 20))              // f32 [8][2048]         65,536
#define L4P_OFF   (((size_t)(1u << 20)) + 131072)   // f32 [8][15][240]     115,200
#define C1T_OFF   (((size_t)(1u << 20)) + 524288)   // fp16 [64][64]          8,192
#define C2T_OFF   (((size_t)(1u << 20)) + 589824)   // fp16 [128][1120]     286,720
#define C3T_OFF   ((size_t)(2u << 20))              // fp16 [1024][2240]  4,587,520
#define C4T_OFF   ((size_t)(7u << 20))              // f32  [40][38400]   6,144,000
#define SEGP_OFF  ((size_t)(13u << 20))             // f32 [2][64][1024]    524,288
#define X1_OFF    ((size_t)(14u << 20))             // f32 [8192][128]    4,194,304
#define H1_OFF    ((size_t)(19u << 20))             // f32 [163840][64]  41,943,040
#define X_OFF     ((size_t)(19u << 20))             // f32 [8192][1024]  (overlaps dead h1)
#define H2_OFF    ((size_t)(61u << 20))             // fp16 [163840][128] 41,943,040
// peak ~103 MB

// ---------------- dtype detector -------------------------------------------
__global__ void detect_kernel(const void* __restrict__ pos,
                              int* __restrict__ flag) {
  int t = threadIdx.x;  // 64 threads
  float a = fabsf(((const float*)pos)[t]);
  bool ok = (a > 1.0e-3f && a < 100.0f);
  unsigned long long m = __ballot(ok);
  if (t == 0) *flag = (__popcll(m) >= 32) ? 1 : 0;  // 1 = fp32 externals
}

// ---------------- coeff transpose: c[part][o][w][i][g] -> ct[o][f] ----------
// f = ((w*W+i)*5 + g)*2 + part ; pad f>=Kt with zeros (layer1 pads 60->64)
// outf32: write fp32 (layer 4) else fp16 bits
__global__ void tkan_kernel(const void* __restrict__ src, void* __restrict__ dst,
                            int dout, int nw, int W, int total, int KPAD,
                            int outf32, const int* __restrict__ dfl) {
  int id = blockIdx.x * 256 + threadIdx.x;
  if (id >= total) return;
  const bool f32 = (*dfl != 0);
  int o = id / KPAD, f = id % KPAD;
  int Kt = nw * W * 10;
  float v = 0.f;
  if (f < Kt) {
    int part = f & 1, q = f >> 1;
    int gg = q % 5, a2 = q / 5;
    int i = a2 % W, w = a2 / W;
    int OS = nw * W * 5;
    size_t sidx = (size_t)part * (dout * OS) + (size_t)o * OS + w * (W * 5) + i * 5 + gg;
    v = ldf(src, sidx, f32);
  }
  if (outf32) ((float*)dst)[id] = v;
  else        ((u16*)dst)[id] = f2h(v);
}

// ---------------- brute-force kNN: one wave per query -----------------------
__global__ __launch_bounds__(256) void knn_kernel(const void* __restrict__ pos,
                                                  int* __restrict__ nbr,
                                                  const int* __restrict__ dfl) {
  __shared__ float px[1024], py[1024], pz[1024];
  const bool f32 = (*dfl != 0);
  const int t = threadIdx.x;
  const int b = blockIdx.y;
  const int base = b << 10;
  for (int j = t; j < 1024; j += 256) {
    size_t pidx = (size_t)(base + j) * 3;
    px[j] = ldf(pos, pidx, f32);
    py[j] = ldf(pos, pidx + 1, f32);
    pz[j] = ldf(pos, pidx + 2, f32);
  }
  __syncthreads();
  const int wv = t >> 6, lane = t & 63;
  const int q = blockIdx.x * 4 + wv;
  const float qx = px[q], qy = py[q], qz = pz[q];
  u64 key[16];
#pragma unroll
  for (int s = 0; s < 16; ++s) {
    const int j = s * 64 + lane;
    float dx = qx - px[j], dy = qy - py[j], dz = qz - pz[j];
    float d = __fadd_rn(__fadd_rn(__fmul_rn(dx, dx), __fmul_rn(dy, dy)),
                        __fmul_rn(dz, dz));
    key[s] = (j == q) ? ~0ull
                      : ((((u64)__float_as_uint(d)) << 32) | (u32)j);
  }
  const int obase = (base + q) * 20;
  for (int k = 0; k < 20; ++k) {
    u64 m = key[0];
#pragma unroll
    for (int s = 1; s < 16; ++s) m = minu64(m, key[s]);
#pragma unroll
    for (int off = 32; off >= 1; off >>= 1) {
      u32 lo = (u32)m, hi = (u32)(m >> 32);
      lo = __shfl_xor(lo, off, 64);
      hi = __shfl_xor(hi, off, 64);
      m = minu64(m, (((u64)hi) << 32) | lo);
    }
    if (lane == 0) nbr[obase + k] = (int)(u32)m;
#pragma unroll
    for (int s = 0; s < 16; ++s)
      if (key[s] == m) key[s] = ~0ull;  // idx embedded -> unique, safe
  }
}

// ---------------- barrier-free MFMA KAN layer (L=1,2,3) ---------------------
// Block = 4 waves; wave wv owns rows [tile*256 + wv*64 .. +64) x NT cols.
// Lane (m16,kb) builds its A-fragment in registers: pairs c*16+kb*4+{0..3}
// of row ..+m16 -> (cos,sin) packed half8. B-fragment = direct 16B global
// load of ct row (ncol0+nb*16+m16), k-offset c*32+kb*8. No LDS tiles, no
// K-loop barriers. Per-pair tables (hidx, ham*kf) in LDS, built once.
template <int L>
__global__ __launch_bounds__(256, 2) void kan_kernel(
    const void* __restrict__ in_, const int* __restrict__ nbr,
    const void* __restrict__ pos, const u16* __restrict__ ct,
    const void* __restrict__ bias, void* __restrict__ out_,
    const int* __restrict__ dfl) {
  constexpr int W    = (L == 1) ? 3  : (L == 2) ? 16  : 32;
  constexpr int S    = (L == 1) ? 3  : (L == 2) ? 8   : 16;
  constexpr int DIN  = (L == 1) ? 6  : (L == 2) ? 64  : 128;
  constexpr int DOUT = (L == 1) ? 64 : (L == 2) ? 128 : 1024;
  constexpr int NT   = (L == 1) ? 64 : 128;
  constexpr int NW   = (DIN - W) / S + 1;
  constexpr int NPAIR = NW * W * 5;                 // (angle,harmonic) pairs
  constexpr int KROW  = (L == 1) ? 64 : NPAIR * 2;  // ct row stride (padded L1)
  constexpr int NCH   = KROW / 32;
  constexpr int NB    = NT / 16;
  constexpr int TPAIR = KROW / 2;

  __shared__ float wTs[TPAIR];   // ham[i] * kf  (0 for padded pairs)
  __shared__ int   hTs[TPAIR];   // input column index (aa for L1)

  const bool f32 = (*dfl != 0);
  const float* inF = (const float*)in_;
  const int t = threadIdx.x;
  for (int pgi = t; pgi < TPAIR; pgi += 256) {
    float wv_ = 0.f; int hx = 0;
    if (pgi < NPAIR) {
      int gg = pgi % 5, aa = pgi / 5;
      int i = aa % W, w = aa / W;
      float hm = 0.54f - 0.46f * cospif(2.0f * (float)i / (float)(W - 1));
      wv_ = hm * (float)(gg + 1);
      hx = S * w + i;
    }
    wTs[pgi] = wv_; hTs[pgi] = hx;
  }
  __syncthreads();

  const int tile = blockIdx.x;
  const int ncol0 = blockIdx.y * NT;
  const int lane = t & 63, wv = t >> 6;
  const int m16 = lane & 15, kb = lane >> 4;
  const int rbase = tile * 256 + wv * 64 + m16;

  f32x4 acc[4][NB];
#pragma unroll
  for (int mb = 0; mb < 4; ++mb)
#pragma unroll
    for (int nb = 0; nb < NB; ++nb) {
      acc[mb][nb][0] = 0.f; acc[mb][nb][1] = 0.f;
      acc[mb][nb][2] = 0.f; acc[mb][nb][3] = 0.f;
    }

  for (int c = 0; c < NCH; ++c) {
    const int pg0 = c * 16 + kb * 4;
    float wm[4]; int hx[4];
#pragma unroll
    for (int u = 0; u < 4; ++u) { wm[u] = wTs[pg0 + u]; hx[u] = hTs[pg0 + u]; }
    half8 af[4];
#pragma unroll
    for (int mb = 0; mb < 4; ++mb) {
      const int row = rbase + mb * 16;
      if constexpr (L == 1) {
        const int pt = row / 20;
        const int cloud = pt >> 10, ci = pt & 1023;
        const int cb = cloud << 10;
        const int jl = nbr[row];
#pragma unroll
        for (int u = 0; u < 4; ++u) {
          const int aa = hx[u];
          float v;
          if (aa < 3) {
            v = ldf(pos, (size_t)(cb + ci) * 3 + aa, f32);
          } else {
            const int cc2 = aa - 3;
            v = ldf(pos, (size_t)(cb + jl) * 3 + cc2, f32) -
                ldf(pos, (size_t)(cb + ci) * 3 + cc2, f32);
          }
          const float ang = v * wm[u];
          af[mb][2 * u]     = (_Float16)__cosf(ang);
          af[mb][2 * u + 1] = (_Float16)__sinf(ang);
        }
      } else {
        const float* rp = inF + (size_t)row * DIN;
#pragma unroll
        for (int u = 0; u < 4; ++u) {
          const float ang = rp[hx[u]] * wm[u];
          af[mb][2 * u]     = (_Float16)__cosf(ang);
          af[mb][2 * u + 1] = (_Float16)__sinf(ang);
        }
      }
    }
#pragma unroll
    for (int nb = 0; nb < NB; ++nb) {
      const half8 bv = *(const half8*)(ct +
          (size_t)(ncol0 + nb * 16 + m16) * KROW + c * 32 + kb * 8);
#pragma unroll
      for (int mb = 0; mb < 4; ++mb)
        acc[mb][nb] = __builtin_amdgcn_mfma_f32_16x16x32_f16(
            af[mb], bv, acc[mb][nb], 0, 0, 0);
    }
  }
  // ---- epilogue: D row=(lane>>4)*4+r, col=lane&15 ; + bias ----
#pragma unroll
  for (int mb = 0; mb < 4; ++mb) {
    const int rowb = tile * 256 + wv * 64 + mb * 16 + kb * 4;
#pragma unroll
    for (int nb = 0; nb < NB; ++nb) {
      const int col = ncol0 + nb * 16 + m16;
      const float bsv = ldf(bias, col, f32);
#pragma unroll
      for (int r = 0; r < 4; ++r) {
        const float ov = acc[mb][nb][r] + bsv;
        if constexpr (L == 2)
          ((u16*)out_)[(size_t)(rowb + r) * DOUT + col] = f2h(ov);
        else
          ((float*)out_)[(size_t)(rowb + r) * DOUT + col] = ov;
      }
    }
  }
}

// ---------------- max over K=20 neighbors (fp16 in, f32 out) ----------------
__global__ void maxk_kernel(const u16* __restrict__ h2, float* __restrict__ x1) {
  int id = blockIdx.x * 256 + threadIdx.x;  // 8192*128 total
  int pcol = id & 127, pt = id >> 7;
  const u16* hp = h2 + (size_t)pt * 2560 + pcol;
  float m = -3.0e38f;
#pragma unroll
  for (int kk = 0; kk < 20; ++kk) m = fmaxf(m, h2f(hp[kk * 128]));
  x1[(size_t)pt * 128 + pcol] = m;
}

// ---------------- segment max + mean: partial (256 blocks) + combine --------
__global__ void seg1_kernel(const float* __restrict__ x,
                            float* __restrict__ pmax,
                            float* __restrict__ psum) {
  const int t = threadIdx.x;
  const int by = blockIdx.y;            // b*8 + rchunk
  const int b = by >> 3, rc = by & 7;
  const int col = blockIdx.x * 256 + t;
  const float* xp = x + ((size_t)(b << 10) + rc * 128) * 1024 + col;
  float m = -3.0e38f, s = 0.f;
  for (int r = 0; r < 128; ++r) {
    float v = xp[(size_t)r * 1024];
    m = fmaxf(m, v);
    s += v;
  }
  pmax[(size_t)by * 1024 + col] = m;
  psum[(size_t)by * 1024 + col] = s;
}

__global__ void seg2_kernel(const float* __restrict__ pmax,
                            const float* __restrict__ psum,
                            float* __restrict__ xg) {
  const int id = blockIdx.x * 256 + threadIdx.x;  // 8192
  const int b = id >> 10, col = id & 1023;
  float m = -3.0e38f, s = 0.f;
#pragma unroll
  for (int rc = 0; rc < 8; ++rc) {
    m = fmaxf(m, pmax[(size_t)(b * 8 + rc) * 1024 + col]);
    s += psum[(size_t)(b * 8 + rc) * 1024 + col];
  }
  xg[b * 2048 + col] = m;
  xg[b * 2048 + 1024 + col] = s * (1.0f / 1024.0f);
}

// ---------------- layer 4 partials: one WG per (window, batch) --------------
__global__ __launch_bounds__(256) void l4_kernel(const float* __restrict__ xg,
                                                 const float* __restrict__ c4t,
                                                 float* __restrict__ part) {
  __shared__ float F[2560];
  const int t = threadIdx.x;
  const int w = blockIdx.x, b = blockIdx.y;
  const float xv = xg[b * 2048 + w * 128 + t];
  const float hm = 0.54f - 0.46f * cospif(2.0f * (float)t / 255.0f);
  const float aa = xv * hm;
#pragma unroll
  for (int gg = 0; gg < 5; ++gg) {
    const float arg = aa * (float)(gg + 1);
    F[t * 10 + gg * 2] = __cosf(arg);
    F[t * 10 + gg * 2 + 1] = __sinf(arg);
  }
  __syncthreads();
  if (t < 240) {
    const int o = t % 40, s = t / 40;
    const int f0 = s * 432;
    const int f1 = (f0 + 432 < 2560) ? (f0 + 432) : 2560;
    const float* cp = c4t + (size_t)o * 38400 + w * 2560;
    float acc = 0.f;
    for (int f = f0; f < f1; f += 4) {
      const float4 cv = *(const float4*)&cp[f];
      const float4 fa = *(const float4*)&F[f];
      acc += fa.x * cv.x + fa.y * cv.y + fa.z * cv.z + fa.w * cv.w;
    }
    part[((b * 15 + w) * 6 + s) * 40 + o] = acc;
  }
}

__global__ void outred_kernel(const float* __restrict__ part,
                              const void* __restrict__ b4,
                              void* __restrict__ outp,
                              const int* __restrict__ dfl) {
  int t = threadIdx.x;
  if (t >= 320) return;
  const bool f32 = (*dfl != 0);
  int b = t / 40, o = t % 40;
  float s = ldf(b4, o, f32);
  for (int w = 0; w < 15; ++w)
#pragma unroll
    for (int sl = 0; sl < 6; ++sl)
      s += part[((b * 15 + w) * 6 + sl) * 40 + o];
  if (f32) ((float*)outp)[t] = s;
  else     ((u16*)outp)[t] = f2bfr(s);
}

// ---------------------------------------------------------------------------
extern "C" void kernel_launch(void* const* d_in, const int* in_sizes, int n_in,
                              void* d_out, int out_size, void* d_ws,
                              size_t ws_size, hipStream_t stream) {
  (void)in_sizes; (void)n_in; (void)out_size; (void)ws_size;
  const void* pos = d_in[0];
  // d_in[1] = batch (int32) -- clouds are sorted equal-size, used implicitly
  const void* c1 = d_in[2];
  const void* b1 = d_in[3];
  const void* c2 = d_in[4];
  const void* b2 = d_in[5];
  const void* c3 = d_in[6];
  const void* b3 = d_in[7];
  const void* c4 = d_in[8];
  const void* b4 = d_in[9];

  char* ws = (char*)d_ws;
  int* nbr   = (int*)(ws + NBR_OFF);
  int* flag  = (int*)(ws + FLAG_OFF);
  float* xg  = (float*)(ws + XG_OFF);
  float* l4p = (float*)(ws + L4P_OFF);
  u16* c1t   = (u16*)(ws + C1T_OFF);
  u16* c2t   = (u16*)(ws + C2T_OFF);
  u16* c3t   = (u16*)(ws + C3T_OFF);
  float* c4t = (float*)(ws + C4T_OFF);
  float* pmax = (float*)(ws + SEGP_OFF);
  float* psum = (float*)(ws + SEGP_OFF + 262144);
  float* x1  = (float*)(ws + X1_OFF);
  float* h1  = (float*)(ws + H1_OFF);
  float* x   = (float*)(ws + X_OFF);
  u16* h2    = (u16*)(ws + H2_OFF);

  detect_kernel<<<1, 64, 0, stream>>>(pos, flag);

  tkan_kernel<<<16, 256, 0, stream>>>(c1, c1t, 64, 2, 3, 64 * 64, 64, 0, flag);
  tkan_kernel<<<560, 256, 0, stream>>>(c2, c2t, 128, 7, 16, 128 * 1120, 1120, 0, flag);
  tkan_kernel<<<8960, 256, 0, stream>>>(c3, c3t, 1024, 7, 32, 1024 * 2240, 2240, 0, flag);
  tkan_kernel<<<6000, 256, 0, stream>>>(c4, c4t, 40, 15, 256, 40 * 38400, 38400, 1, flag);

  knn_kernel<<<dim3(256, 8), 256, 0, stream>>>(pos, nbr, flag);

  kan_kernel<1><<<640, 256, 0, stream>>>(nullptr, nbr, pos, c1t, b1, h1, flag);
  kan_kernel<2><<<640, 256, 0, stream>>>(h1, nullptr, nullptr, c2t, b2, h2, flag);
  maxk_kernel<<<4096, 256, 0, stream>>>(h2, x1);
  kan_kernel<3><<<dim3(32, 8), 256, 0, stream>>>(x1, nullptr, nullptr, c3t, b3, x, flag);

  seg1_kernel<<<dim3(4, 64), 256, 0, stream>>>(x, pmax, psum);
  seg2_kernel<<<32, 256, 0, stream>>>(pmax, psum, xg);
  l4_kernel<<<dim3(15, 8), 256, 0, stream>>>(xg, c4t, l4p);
  outred_kernel<<<1, 320, 0, stream>>>(l4p, b4, d_out, flag);
}

// Round 11
// 446.466 us; speedup vs baseline: 1.4833x; 1.4833x over previous
//
#include <hip/hip_runtime.h>

// ---------------------------------------------------------------------------
// STFT-Fourier-KAN DGCNN on MI355X.
// R10 post-mortem: barrier-free kan (R9) REGRESSED 211->275 us. Counters:
// ~90% latency stall -- 16 scattered global gathers/lane/chunk against
// h1 (42MB, L2-overflow -> ~900cyc HBM) sit on the MFMA critical path.
// R11: per-wave PRIVATE LDS input slab, staged once with coalesced float4
// (padded stride DIN+4 -> <=4-way LDS aliasing), K-loop = B-loads issued
// first (L2-resident ct), features from LDS + cos/sin (covers B latency),
// MFMA. No barriers (slabs are wave-private). kan<3> uses 32 rows/wave so
// 2 blocks/CU fit LDS. kan<1> keeps direct gather (pos is L2-resident).
// ---------------------------------------------------------------------------

typedef unsigned short u16;
typedef unsigned int   u32;
typedef unsigned long long u64;
typedef __attribute__((ext_vector_type(8))) _Float16 half8;
typedef __attribute__((ext_vector_type(4))) float f32x4;

__device__ __forceinline__ float bf2f(u16 u) {
  u32 v = ((u32)u) << 16;
  return __uint_as_float(v);
}
__device__ __forceinline__ u16 f2bfr(float f) {  // bf16 round-to-nearest-even
  u32 x = __float_as_uint(f);
  u32 r = x + 0x7FFFu + ((x >> 16) & 1u);
  return (u16)(r >> 16);
}
__device__ __forceinline__ u16 f2h(float f) {    // fp16 RTN bits
  _Float16 h = (_Float16)f;
  u16 r;
  __builtin_memcpy(&r, &h, 2);
  return r;
}
__device__ __forceinline__ float h2f(u16 u) {
  _Float16 h;
  __builtin_memcpy(&h, &u, 2);
  return (float)h;
}
// dtype-dispatched external load (flag wave-uniform -> scalar branch)
__device__ __forceinline__ float ldf(const void* p, size_t i, bool f32) {
  return f32 ? ((const float*)p)[i] : bf2f(((const u16*)p)[i]);
}
__device__ __forceinline__ u64 minu64(u64 a, u64 b) { return a < b ? a : b; }

// ---------------- workspace layout (bytes) ----------------
#define NBR_OFF   ((size_t)0)                       // int32 [163840]       655,360
#define FLAG_OFF  ((size_t)917504)                  // int32 [1]
#define XG_OFF    ((size_t)(1u << 20))              // f32 [8][2048]         65,536
#define L4P_OFF   (((size_t)(1u << 20)) + 131072)   // f32 [8][15][240]     115,200
#define C1T_OFF   (((size_t)(1u << 20)) + 524288)   // fp16 [64][64]          8,192
#define C2T_OFF   (((size_t)(1u << 20)) + 589824)   // fp16 [128][1120]     286,720
#define C3T_OFF   ((size_t)(2u << 20))              // fp16 [1024][2240]  4,587,520
#define C4T_OFF   ((size_t)(7u << 20))              // f32  [40][38400]   6,144,000
#define SEGP_OFF  ((size_t)(13u << 20))             // f32 [2][64][1024]    524,288
#define X1_OFF    ((size_t)(14u << 20))             // f32 [8192][128]    4,194,304
#define H1_OFF    ((size_t)(19u << 20))             // f32 [163840][64]  41,943,040
#define X_OFF     ((size_t)(19u << 20))             // f32 [8192][1024]  (overlaps dead h1)
#define H2_OFF    ((size_t)(61u << 20))             // fp16 [163840][128] 41,943,040
// peak ~103 MB

// ---------------- dtype detector -------------------------------------------
__global__ void detect_kernel(const void* __restrict__ pos,
                              int* __restrict__ flag) {
  int t = threadIdx.x;  // 64 threads
  float a = fabsf(((const float*)pos)[t]);
  bool ok = (a > 1.0e-3f && a < 100.0f);
  unsigned long long m = __ballot(ok);
  if (t == 0) *flag = (__popcll(m) >= 32) ? 1 : 0;  // 1 = fp32 externals
}

// ---------------- coeff transpose: c[part][o][w][i][g] -> ct[o][f] ----------
__global__ void tkan_kernel(const void* __restrict__ src, void* __restrict__ dst,
                            int dout, int nw, int W, int total, int KPAD,
                            int outf32, const int* __restrict__ dfl) {
  int id = blockIdx.x * 256 + threadIdx.x;
  if (id >= total) return;
  const bool f32 = (*dfl != 0);
  int o = id / KPAD, f = id % KPAD;
  int Kt = nw * W * 10;
  float v = 0.f;
  if (f < Kt) {
    int part = f & 1, q = f >> 1;
    int gg = q % 5, a2 = q / 5;
    int i = a2 % W, w = a2 / W;
    int OS = nw * W * 5;
    size_t sidx = (size_t)part * (dout * OS) + (size_t)o * OS + w * (W * 5) + i * 5 + gg;
    v = ldf(src, sidx, f32);
  }
  if (outf32) ((float*)dst)[id] = v;
  else        ((u16*)dst)[id] = f2h(v);
}

// ---------------- brute-force kNN: one wave per query -----------------------
__global__ __launch_bounds__(256) void knn_kernel(const void* __restrict__ pos,
                                                  int* __restrict__ nbr,
                                                  const int* __restrict__ dfl) {
  __shared__ float px[1024], py[1024], pz[1024];
  const bool f32 = (*dfl != 0);
  const int t = threadIdx.x;
  const int b = blockIdx.y;
  const int base = b << 10;
  for (int j = t; j < 1024; j += 256) {
    size_t pidx = (size_t)(base + j) * 3;
    px[j] = ldf(pos, pidx, f32);
    py[j] = ldf(pos, pidx + 1, f32);
    pz[j] = ldf(pos, pidx + 2, f32);
  }
  __syncthreads();
  const int wv = t >> 6, lane = t & 63;
  const int q = blockIdx.x * 4 + wv;
  const float qx = px[q], qy = py[q], qz = pz[q];
  u64 key[16];
#pragma unroll
  for (int s = 0; s < 16; ++s) {
    const int j = s * 64 + lane;
    float dx = qx - px[j], dy = qy - py[j], dz = qz - pz[j];
    float d = __fadd_rn(__fadd_rn(__fmul_rn(dx, dx), __fmul_rn(dy, dy)),
                        __fmul_rn(dz, dz));
    key[s] = (j == q) ? ~0ull
                      : ((((u64)__float_as_uint(d)) << 32) | (u32)j);
  }
  const int obase = (base + q) * 20;
  for (int k = 0; k < 20; ++k) {
    u64 m = key[0];
#pragma unroll
    for (int s = 1; s < 16; ++s) m = minu64(m, key[s]);
#pragma unroll
    for (int off = 32; off >= 1; off >>= 1) {
      u32 lo = (u32)m, hi = (u32)(m >> 32);
      lo = __shfl_xor(lo, off, 64);
      hi = __shfl_xor(hi, off, 64);
      m = minu64(m, (((u64)hi) << 32) | lo);
    }
    if (lane == 0) nbr[obase + k] = (int)(u32)m;
#pragma unroll
    for (int s = 0; s < 16; ++s)
      if (key[s] == m) key[s] = ~0ull;  // idx embedded -> unique, safe
  }
}

// ---------------- MFMA KAN layer, wave-private LDS input slab ---------------
// Wave wv owns RW rows; slab staged once, coalesced float4, stride DIN+4.
// K-loop: B global loads issued first (L2-resident), features from LDS +
// cos/sin (covers B latency), MFMA. No __syncthreads after the table build.
template <int L>
__global__ __launch_bounds__(256, 2) void kan_kernel(
    const void* __restrict__ in_, const int* __restrict__ nbr,
    const void* __restrict__ pos, const u16* __restrict__ ct,
    const void* __restrict__ bias, void* __restrict__ out_,
    const int* __restrict__ dfl) {
  constexpr int W    = (L == 1) ? 3  : (L == 2) ? 16  : 32;
  constexpr int S    = (L == 1) ? 3  : (L == 2) ? 8   : 16;
  constexpr int DIN  = (L == 1) ? 6  : (L == 2) ? 64  : 128;
  constexpr int DOUT = (L == 1) ? 64 : (L == 2) ? 128 : 1024;
  constexpr int NT   = (L == 1) ? 64 : 128;
  constexpr int NW   = (DIN - W) / S + 1;
  constexpr int NPAIR = NW * W * 5;                 // (angle,harmonic) pairs
  constexpr int KROW  = (L == 1) ? 64 : NPAIR * 2;  // ct row stride (padded L1)
  constexpr int NCH   = KROW / 32;
  constexpr int NB    = NT / 16;
  constexpr int TPAIR = KROW / 2;
  constexpr int RW    = (L == 3) ? 32 : 64;         // rows per wave
  constexpr int MB    = RW / 16;
  constexpr int PST   = DIN + 4;                    // slab stride (floats)

  __shared__ float wTs[TPAIR];   // ham[i] * kf  (0 for padded pairs)
  __shared__ int   hTs[TPAIR];   // input column index (aa for L1)
  __shared__ float slab[(L == 1) ? 1 : 4 * RW * PST];

  const bool f32 = (*dfl != 0);
  const float* inF = (const float*)in_;
  const int t = threadIdx.x;
  for (int pgi = t; pgi < TPAIR; pgi += 256) {
    float wv_ = 0.f; int hx = 0;
    if (pgi < NPAIR) {
      int gg = pgi % 5, aa = pgi / 5;
      int i = aa % W, w = aa / W;
      float hm = 0.54f - 0.46f * cospif(2.0f * (float)i / (float)(W - 1));
      wv_ = hm * (float)(gg + 1);
      hx = S * w + i;
    }
    wTs[pgi] = wv_; hTs[pgi] = hx;
  }
  __syncthreads();

  const int tile = blockIdx.x;
  const int ncol0 = blockIdx.y * NT;
  const int lane = t & 63, wv = t >> 6;
  const int m16 = lane & 15, kb = lane >> 4;
  const int rowbase = tile * (4 * RW) + wv * RW;
  float* myslab = &slab[(L == 1) ? 0 : wv * RW * PST];

  // ---- stage wave-private input slab (L>=2), coalesced float4 ----
  if constexpr (L >= 2) {
    constexpr int F4R = DIN / 4;
    constexpr int TOT = RW * F4R;
    for (int i = lane; i < TOT; i += 64) {
      const int r = i / F4R, c4 = i % F4R;
      const float4 v = *(const float4*)(inF + (size_t)(rowbase + r) * DIN + c4 * 4);
      *(float4*)(myslab + r * PST + c4 * 4) = v;
    }
  }

  f32x4 acc[MB][NB];
#pragma unroll
  for (int mb = 0; mb < MB; ++mb)
#pragma unroll
    for (int nb = 0; nb < NB; ++nb) {
      acc[mb][nb][0] = 0.f; acc[mb][nb][1] = 0.f;
      acc[mb][nb][2] = 0.f; acc[mb][nb][3] = 0.f;
    }

  for (int c = 0; c < NCH; ++c) {
    // ---- issue B loads first (latency covered by the trans chain) ----
    half8 bv[NB];
#pragma unroll
    for (int nb = 0; nb < NB; ++nb)
      bv[nb] = *(const half8*)(ct +
          (size_t)(ncol0 + nb * 16 + m16) * KROW + c * 32 + kb * 8);
    // ---- A features from LDS (or pos gather for L1) ----
    const int pg0 = c * 16 + kb * 4;
    float wm[4]; int hx[4];
#pragma unroll
    for (int u = 0; u < 4; ++u) { wm[u] = wTs[pg0 + u]; hx[u] = hTs[pg0 + u]; }
    half8 af[MB];
#pragma unroll
    for (int mb = 0; mb < MB; ++mb) {
      const int row = rowbase + mb * 16 + m16;
      if constexpr (L == 1) {
        const int pt = row / 20;
        const int cloud = pt >> 10, ci = pt & 1023;
        const int cb = cloud << 10;
        const int jl = nbr[row];
#pragma unroll
        for (int u = 0; u < 4; ++u) {
          const int aa = hx[u];
          float v;
          if (aa < 3) {
            v = ldf(pos, (size_t)(cb + ci) * 3 + aa, f32);
          } else {
            const int cc2 = aa - 3;
            v = ldf(pos, (size_t)(cb + jl) * 3 + cc2, f32) -
                ldf(pos, (size_t)(cb + ci) * 3 + cc2, f32);
          }
          const float ang = v * wm[u];
          af[mb][2 * u]     = (_Float16)__cosf(ang);
          af[mb][2 * u + 1] = (_Float16)__sinf(ang);
        }
      } else {
        const float* rp = myslab + (mb * 16 + m16) * PST;
#pragma unroll
        for (int u = 0; u < 4; ++u) {
          const float ang = rp[hx[u]] * wm[u];
          af[mb][2 * u]     = (_Float16)__cosf(ang);
          af[mb][2 * u + 1] = (_Float16)__sinf(ang);
        }
      }
    }
#pragma unroll
    for (int nb = 0; nb < NB; ++nb)
#pragma unroll
      for (int mb = 0; mb < MB; ++mb)
        acc[mb][nb] = __builtin_amdgcn_mfma_f32_16x16x32_f16(
            af[mb], bv[nb], acc[mb][nb], 0, 0, 0);
  }
  // ---- epilogue: D row=(lane>>4)*4+r, col=lane&15 ; + bias ----
#pragma unroll
  for (int mb = 0; mb < MB; ++mb) {
    const int rowb = rowbase + mb * 16 + kb * 4;
#pragma unroll
    for (int nb = 0; nb < NB; ++nb) {
      const int col = ncol0 + nb * 16 + m16;
      const float bsv = ldf(bias, col, f32);
#pragma unroll
      for (int r = 0; r < 4; ++r) {
        const float ov = acc[mb][nb][r] + bsv;
        if constexpr (L == 2)
          ((u16*)out_)[(size_t)(rowb + r) * DOUT + col] = f2h(ov);
        else
          ((float*)out_)[(size_t)(rowb + r) * DOUT + col] = ov;
      }
    }
  }
}

// ---------------- max over K=20 neighbors (fp16 in, f32 out) ----------------
__global__ void maxk_kernel(const u16* __restrict__ h2, float* __restrict__ x1) {
  int id = blockIdx.x * 256 + threadIdx.x;  // 8192*128 total
  int pcol = id & 127, pt = id >> 7;
  const u16* hp = h2 + (size_t)pt * 2560 + pcol;
  float m = -3.0e38f;
#pragma unroll
  for (int kk = 0; kk < 20; ++kk) m = fmaxf(m, h2f(hp[kk * 128]));
  x1[(size_t)pt * 128 + pcol] = m;
}

// ---------------- segment max + mean: partial (256 blocks) + combine --------
__global__ void seg1_kernel(const float* __restrict__ x,
                            float* __restrict__ pmax,
                            float* __restrict__ psum) {
  const int t = threadIdx.x;
  const int by = blockIdx.y;            // b*8 + rchunk
  const int b = by >> 3, rc = by & 7;
  const int col = blockIdx.x * 256 + t;
  const float* xp = x + ((size_t)(b << 10) + rc * 128) * 1024 + col;
  float m = -3.0e38f, s = 0.f;
  for (int r = 0; r < 128; ++r) {
    float v = xp[(size_t)r * 1024];
    m = fmaxf(m, v);
    s += v;
  }
  pmax[(size_t)by * 1024 + col] = m;
  psum[(size_t)by * 1024 + col] = s;
}

__global__ void seg2_kernel(const float* __restrict__ pmax,
                            const float* __restrict__ psum,
                            float* __restrict__ xg) {
  const int id = blockIdx.x * 256 + threadIdx.x;  // 8192
  const int b = id >> 10, col = id & 1023;
  float m = -3.0e38f, s = 0.f;
#pragma unroll
  for (int rc = 0; rc < 8; ++rc) {
    m = fmaxf(m, pmax[(size_t)(b * 8 + rc) * 1024 + col]);
    s += psum[(size_t)(b * 8 + rc) * 1024 + col];
  }
  xg[b * 2048 + col] = m;
  xg[b * 2048 + 1024 + col] = s * (1.0f / 1024.0f);
}

// ---------------- layer 4 partials: one WG per (window, batch) --------------
__global__ __launch_bounds__(256) void l4_kernel(const float* __restrict__ xg,
                                                 const float* __restrict__ c4t,
                                                 float* __restrict__ part) {
  __shared__ float F[2560];
  const int t = threadIdx.x;
  const int w = blockIdx.x, b = blockIdx.y;
  const float xv = xg[b * 2048 + w * 128 + t];
  const float hm = 0.54f - 0.46f * cospif(2.0f * (float)t / 255.0f);
  const float aa = xv * hm;
#pragma unroll
  for (int gg = 0; gg < 5; ++gg) {
    const float arg = aa * (float)(gg + 1);
    F[t * 10 + gg * 2] = __cosf(arg);
    F[t * 10 + gg * 2 + 1] = __sinf(arg);
  }
  __syncthreads();
  if (t < 240) {
    const int o = t % 40, s = t / 40;
    const int f0 = s * 432;
    const int f1 = (f0 + 432 < 2560) ? (f0 + 432) : 2560;
    const float* cp = c4t + (size_t)o * 38400 + w * 2560;
    float acc = 0.f;
    for (int f = f0; f < f1; f += 4) {
      const float4 cv = *(const float4*)&cp[f];
      const float4 fa = *(const float4*)&F[f];
      acc += fa.x * cv.x + fa.y * cv.y + fa.z * cv.z + fa.w * cv.w;
    }
    part[((b * 15 + w) * 6 + s) * 40 + o] = acc;
  }
}

__global__ void outred_kernel(const float* __restrict__ part,
                              const void* __restrict__ b4,
                              void* __restrict__ outp,
                              const int* __restrict__ dfl) {
  int t = threadIdx.x;
  if (t >= 320) return;
  const bool f32 = (*dfl != 0);
  int b = t / 40, o = t % 40;
  float s = ldf(b4, o, f32);
  for (int w = 0; w < 15; ++w)
#pragma unroll
    for (int sl = 0; sl < 6; ++sl)
      s += part[((b * 15 + w) * 6 + sl) * 40 + o];
  if (f32) ((float*)outp)[t] = s;
  else     ((u16*)outp)[t] = f2bfr(s);
}

// ---------------------------------------------------------------------------
extern "C" void kernel_launch(void* const* d_in, const int* in_sizes, int n_in,
                              void* d_out, int out_size, void* d_ws,
                              size_t ws_size, hipStream_t stream) {
  (void)in_sizes; (void)n_in; (void)out_size; (void)ws_size;
  const void* pos = d_in[0];
  // d_in[1] = batch (int32) -- clouds are sorted equal-size, used implicitly
  const void* c1 = d_in[2];
  const void* b1 = d_in[3];
  const void* c2 = d_in[4];
  const void* b2 = d_in[5];
  const void* c3 = d_in[6];
  const void* b3 = d_in[7];
  const void* c4 = d_in[8];
  const void* b4 = d_in[9];

  char* ws = (char*)d_ws;
  int* nbr   = (int*)(ws + NBR_OFF);
  int* flag  = (int*)(ws + FLAG_OFF);
  float* xg  = (float*)(ws + XG_OFF);
  float* l4p = (float*)(ws + L4P_OFF);
  u16* c1t   = (u16*)(ws + C1T_OFF);
  u16* c2t   = (u16*)(ws + C2T_OFF);
  u16* c3t   = (u16*)(ws + C3T_OFF);
  float* c4t = (float*)(ws + C4T_OFF);
  float* pmax = (float*)(ws + SEGP_OFF);
  float* psum = (float*)(ws + SEGP_OFF + 262144);
  float* x1  = (float*)(ws + X1_OFF);
  float* h1  = (float*)(ws + H1_OFF);
  float* x   = (float*)(ws + X_OFF);
  u16* h2    = (u16*)(ws + H2_OFF);

  detect_kernel<<<1, 64, 0, stream>>>(pos, flag);

  tkan_kernel<<<16, 256, 0, stream>>>(c1, c1t, 64, 2, 3, 64 * 64, 64, 0, flag);
  tkan_kernel<<<560, 256, 0, stream>>>(c2, c2t, 128, 7, 16, 128 * 1120, 1120, 0, flag);
  tkan_kernel<<<8960, 256, 0, stream>>>(c3, c3t, 1024, 7, 32, 1024 * 2240, 2240, 0, flag);
  tkan_kernel<<<6000, 256, 0, stream>>>(c4, c4t, 40, 15, 256, 40 * 38400, 38400, 1, flag);

  knn_kernel<<<dim3(256, 8), 256, 0, stream>>>(pos, nbr, flag);

  kan_kernel<1><<<640, 256, 0, stream>>>(nullptr, nbr, pos, c1t, b1, h1, flag);
  kan_kernel<2><<<640, 256, 0, stream>>>(h1, nullptr, nullptr, c2t, b2, h2, flag);
  maxk_kernel<<<4096, 256, 0, stream>>>(h2, x1);
  kan_kernel<3><<<dim3(64, 8), 256, 0, stream>>>(x1, nullptr, nullptr, c3t, b3, x, flag);

  seg1_kernel<<<dim3(4, 64), 256, 0, stream>>>(x, pmax, psum);
  seg2_kernel<<<32, 256, 0, stream>>>(pmax, psum, xg);
  l4_kernel<<<dim3(15, 8), 256, 0, stream>>>(xg, c4t, l4p);
  outred_kernel<<<1, 320, 0, stream>>>(l4p, b4, d_out, flag);
}